// Round 1
// baseline (267.171 us; speedup 1.0000x reference)
//
#include <hip/hip_runtime.h>

// Inverse DTCWT (biort legall) — fully fused single kernel.
// out(b,c,256,256) = colfilt(rowfilt(Yl,g0)+rowfilt(hl,g1), g0)
//                  + colfilt(rowfilt(lh,g0)+rowfilt(hh,g1), g1)
// where lh/hl/hh are virtual c2q quads of subband pairs (0,5),(2,3),(1,4).
// Each block: one (b*C+c) plane x 64-row tile. 256 threads = 1 column each.
// Column filter done via 5-row register sliding window; row filters read
// global directly (neighbor taps are L1 hits). c2q never materialized.

#define Hh 256
#define Ww 256
#define H2 128
#define W2 128
#define NS 6
#define SB (H2 * W2)
#define TH 64

__device__ __forceinline__ int reflect_idx(int m, int N) {
    if (m < 0) m = -m - 1;
    if (m >= N) m = 2 * N - 1 - m;
    return m;
}

__global__ __launch_bounds__(256) void dtcwt_inv(
    const float* __restrict__ Yl,
    const float* __restrict__ Yhr,
    const float* __restrict__ Yhi,
    const float* __restrict__ g0o,
    const float* __restrict__ g1o,
    float* __restrict__ out)
{
    const float SC = 0.70710678118654752440f;  // sqrt(0.5)
    const int j = threadIdx.x;        // output column 0..255
    const int plane = blockIdx.x;     // b*C + c, 0..255
    const int i0 = blockIdx.y * TH;   // first output row of this tile

    const float* yl  = Yl  + (size_t)plane * Hh * Ww;
    const float* phr = Yhr + (size_t)plane * NS * SB;
    const float* phi = Yhi + (size_t)plane * NS * SB;
    float* outp = out + (size_t)plane * Hh * Ww;

    // Filter taps (read from device; uniform-address loads, broadcast).
    float g0[3], g1[5];
#pragma unroll
    for (int t = 0; t < 3; ++t) g0[t] = g0o[t];
#pragma unroll
    for (int t = 0; t < 5; ++t) g1[t] = g1o[t];
    // Fold the c2q gain SC into the taps applied to quad images.
    float g0s[3], g1s[5];
#pragma unroll
    for (int t = 0; t < 3; ++t) g0s[t] = g0[t] * SC;
#pragma unroll
    for (int t = 0; t < 5; ++t) g1s[t] = g1[t] * SC;

    // Precompute reflected column indices (fixed per thread).
    const int jm1 = reflect_idx(j - 1, Ww);
    const int jp1 = reflect_idx(j + 1, Ww);
    int qjc[5], qv[5];  // quad-image taps j-2..j+2 -> (subband col, col parity)
#pragma unroll
    for (int t = 0; t < 5; ++t) {
        int jj = reflect_idx(j - 2 + t, Ww);
        qjc[t] = jj >> 1;
        qv[t] = jj & 1;
    }

    float w1[5], w2[5];  // sliding window: y1,y2 at rows i-2..i+2

    // Compute y1,y2 at (row r, column j).
    auto compute_row = [&](int r, float& o1, float& o2) {
        const int ir = r >> 1;
        const int u = r & 1;           // row parity (wave-uniform)
        const float* ylr = yl + r * Ww;
        float y1v = g0[0] * ylr[jm1] + g0[1] * ylr[j] + g0[2] * ylr[jp1];
        const float* pr = phr + ir * W2;
        const float* pi = phi + ir * W2;
        float hl_acc = 0.f, hh_acc = 0.f, lh_acc = 0.f;
#pragma unroll
        for (int t = 0; t < 5; ++t) {
            const int jc = qjc[t];
            const int v = qv[t];
            // c2q: value uses real parts when u==v, imag parts otherwise.
            const float* p = (u == v) ? pr : pi;
            // pair combine: u==0 -> a1+a2 ; u==1,v==0 -> a1-a2 ; u==1,v==1 -> a2-a1
            const float sgn = ((u & v) != 0) ? -1.f : 1.f;
            float h1 = p[2 * SB + jc], h2 = p[3 * SB + jc];  // hl pair (2,3)
            float e1 = p[1 * SB + jc], e2 = p[4 * SB + jc];  // hh pair (1,4)
            float hlv = u ? (h1 - h2) : (h1 + h2);
            float hhv = u ? (e1 - e2) : (e1 + e2);
            float t1 = g1s[t] * sgn;
            hl_acc += t1 * hlv;
            hh_acc += t1 * hhv;
            if (t >= 1 && t <= 3) {
                float l1 = p[0 * SB + jc], l2 = p[5 * SB + jc];  // lh pair (0,5)
                float lhv = u ? (l1 - l2) : (l1 + l2);
                lh_acc += g0s[t - 1] * sgn * lhv;
            }
        }
        o1 = y1v + hl_acc;
        o2 = lh_acc + hh_acc;
    };

    // Prime window with rows i0-2 .. i0+1.
#pragma unroll
    for (int k = 0; k < 4; ++k) {
        int r = reflect_idx(i0 - 2 + k, Hh);
        compute_row(r, w1[k], w2[k]);
    }

    for (int oi = 0; oi < TH; ++oi) {
        int r = reflect_idx(i0 + oi + 2, Hh);
        compute_row(r, w1[4], w2[4]);
        // column filters: g0 over w1 rows (i-1,i,i+1), g1 over w2 rows (i-2..i+2)
        float res = g0[0] * w1[1] + g0[1] * w1[2] + g0[2] * w1[3];
        res += g1[0] * w2[0] + g1[1] * w2[1] + g1[2] * w2[2]
             + g1[3] * w2[3] + g1[4] * w2[4];
        outp[(size_t)(i0 + oi) * Ww + j] = res;
#pragma unroll
        for (int k = 0; k < 4; ++k) { w1[k] = w1[k + 1]; w2[k] = w2[k + 1]; }
    }
}

extern "C" void kernel_launch(void* const* d_in, const int* in_sizes, int n_in,
                              void* d_out, int out_size, void* d_ws, size_t ws_size,
                              hipStream_t stream) {
    const float* Yl  = (const float*)d_in[0];
    const float* Yhr = (const float*)d_in[1];
    const float* Yhi = (const float*)d_in[2];
    const float* g0o = (const float*)d_in[3];
    const float* g1o = (const float*)d_in[4];
    float* outp = (float*)d_out;
    dim3 grid(256, Hh / TH);  // 256 planes x 4 row tiles
    dim3 block(256);
    hipLaunchKernelGGL(dtcwt_inv, grid, block, 0, stream,
                       Yl, Yhr, Yhi, g0o, g1o, outp);
}

// Round 2
// 83.450 us; speedup vs baseline: 3.2016x; 3.2016x over previous
//
#include <hip/hip_runtime.h>
#include <type_traits>

// Inverse DTCWT (biort legall) — fused, LDS-staged.
// Per block: one (b*C+c) plane x TH-row output tile.
// Per subband-row-pair: stage 12 raw subband rows (12x128 f32) + 2 Yl rows
// into LDS with coalesced loads, then every thread computes y1,y2 for both
// row parities from LDS (c2q pair-combine + row filters), feeding a 2-row
// register sliding window for the column filter.

#define Hh 256
#define Ww 256
#define W2 128
#define SB (128 * 128)
#define TH 32  // output rows per block

__device__ __forceinline__ int reflect_idx(int m, int N) {
    if (m < 0) m = -m - 1;
    if (m >= N) m = 2 * N - 1 - m;
    return m;
}

__global__ __launch_bounds__(256) void dtcwt_inv(
    const float* __restrict__ Yl,
    const float* __restrict__ Yhr,
    const float* __restrict__ Yhi,
    const float* __restrict__ g0o,
    const float* __restrict__ g1o,
    float* __restrict__ out)
{
    const float SC = 0.70710678118654752440f;  // sqrt(0.5)

    __shared__ float sub[12 * 128];   // raw subband rows: q=0..5 Yhr, 6..11 Yhi
    __shared__ float ylr[2][256];     // Yl rows 2ip, 2ip+1

    const int j = threadIdx.x;
    const int plane = blockIdx.x;
    const int i0 = blockIdx.y * TH;
    const int ip0 = i0 >> 1;

    const float* yl  = Yl  + (size_t)plane * Hh * Ww;
    const float* phr = Yhr + (size_t)plane * 6 * SB;
    const float* phi = Yhi + (size_t)plane * 6 * SB;
    float* outp = out + (size_t)plane * Hh * Ww;

    float g0[3], g1[5];
#pragma unroll
    for (int t = 0; t < 3; ++t) g0[t] = g0o[t];
#pragma unroll
    for (int t = 0; t < 5; ++t) g1[t] = g1o[t];

    // Per-thread precompute: reflected cols, LDS offsets, signed coefs.
    const int jm1 = reflect_idx(j - 1, Ww);
    const int jp1 = reflect_idx(j + 1, Ww);
    int   soff[2][5];
    float cG1[2][5], cG0[2][3];
#pragma unroll
    for (int t = 0; t < 5; ++t) {
        int jj = reflect_idx(j - 2 + t, Ww);
        int jc = jj >> 1, v = jj & 1;
#pragma unroll
        for (int u = 0; u < 2; ++u) {
            bool im = (u != v);
            soff[u][t] = jc + (im ? 768 : 0);        // +6*128 for imag block
            float sgn = (u && v) ? -1.f : 1.f;
            cG1[u][t] = g1[t] * SC * sgn;
            if (t >= 1 && t <= 3) cG0[u][t - 1] = g0[t - 1] * SC * sgn;
        }
    }

    auto stage = [&](int ip) {
        __syncthreads();  // previous phase's LDS reads done
#pragma unroll
        for (int k2 = 0; k2 < 6; ++k2) {
            int idx = k2 * 256 + j;
            int q = idx >> 7, col = idx & 127;  // q wave-uniform
            const float* bq = (q < 6) ? (phr + (size_t)q * SB)
                                      : (phi + (size_t)(q - 6) * SB);
            sub[q * 128 + col] = bq[ip * W2 + col];
        }
        ylr[0][j] = yl[(2 * ip) * Ww + j];
        ylr[1][j] = yl[(2 * ip + 1) * Ww + j];
        __syncthreads();
    };

    // y1,y2 at row parity u (compile-time) of the staged pair.
    auto compute = [&](auto UC, float& o1, float& o2) {
        constexpr int u = decltype(UC)::value;
        float y1 = g0[0] * ylr[u][jm1] + g0[1] * ylr[u][j] + g0[2] * ylr[u][jp1];
        float y2 = 0.f;
#pragma unroll
        for (int t = 0; t < 5; ++t) {
            const int so = soff[u][t];
            float s1 = sub[256 + so], s2 = sub[384 + so];   // hl pair (2,3)
            float d = u ? (s1 - s2) : (s1 + s2);
            y1 += cG1[u][t] * d;
            float e1 = sub[128 + so], e2 = sub[512 + so];   // hh pair (1,4)
            float f = u ? (e1 - e2) : (e1 + e2);
            y2 += cG1[u][t] * f;
            if (t >= 1 && t <= 3) {
                float l1 = sub[so], l2 = sub[640 + so];     // lh pair (0,5)
                float g = u ? (l1 - l2) : (l1 + l2);
                y2 += cG0[u][t - 1] * g;
            }
        }
        o1 = y1; o2 = y2;
    };
    std::integral_constant<int, 0> U0;
    std::integral_constant<int, 1> U1;

    float h1[4], h2[4];  // y1,y2 at rows r0-2, r0-1, r0, r0+1

    if (i0 == 0) {
        // rows -2,-1 reflect to 1,0 → one stage of pair 0 fills all four.
        stage(0);
        float a1, a2, b1, b2;
        compute(U0, a1, a2);   // row 0
        compute(U1, b1, b2);   // row 1
        h1[0] = b1; h1[1] = a1; h1[2] = a1; h1[3] = b1;
        h2[0] = b2; h2[1] = a2; h2[2] = a2; h2[3] = b2;
    } else {
        float a1, a2, b1, b2;
        stage(ip0 - 1);
        compute(U0, a1, a2); compute(U1, b1, b2);
        h1[0] = a1; h1[1] = b1; h2[0] = a2; h2[1] = b2;
        stage(ip0);
        compute(U0, a1, a2); compute(U1, b1, b2);
        h1[2] = a1; h1[3] = b1; h2[2] = a2; h2[3] = b2;
    }

    for (int k = 0; k < TH / 2; ++k) {
        int ipn = ip0 + 1 + k;
        const bool refl = (ipn > 127);   // rows 256,257 reflect to 255,254
        if (refl) ipn = 127;
        stage(ipn);
        float c1, c2, d1, d2;
        compute(U0, c1, c2);  // row 2*ipn
        compute(U1, d1, d2);  // row 2*ipn+1
        // na0 = y at row r0+2, na1 = y at row r0+3
        float na0_1 = refl ? d1 : c1, na0_2 = refl ? d2 : c2;
        float na1_1 = refl ? c1 : d1, na1_2 = refl ? c2 : d2;

        const int r0 = i0 + 2 * k;
        float o0 = g0[0] * h1[1] + g0[1] * h1[2] + g0[2] * h1[3]
                 + g1[0] * h2[0] + g1[1] * h2[1] + g1[2] * h2[2]
                 + g1[3] * h2[3] + g1[4] * na0_2;
        float o1 = g0[0] * h1[2] + g0[1] * h1[3] + g0[2] * na0_1
                 + g1[0] * h2[1] + g1[1] * h2[2] + g1[2] * h2[3]
                 + g1[3] * na0_2 + g1[4] * na1_2;
        outp[(size_t)r0 * Ww + j] = o0;
        outp[(size_t)(r0 + 1) * Ww + j] = o1;

        h1[0] = h1[2]; h1[1] = h1[3]; h1[2] = na0_1; h1[3] = na1_1;
        h2[0] = h2[2]; h2[1] = h2[3]; h2[2] = na0_2; h2[3] = na1_2;
    }
}

extern "C" void kernel_launch(void* const* d_in, const int* in_sizes, int n_in,
                              void* d_out, int out_size, void* d_ws, size_t ws_size,
                              hipStream_t stream) {
    const float* Yl  = (const float*)d_in[0];
    const float* Yhr = (const float*)d_in[1];
    const float* Yhi = (const float*)d_in[2];
    const float* g0o = (const float*)d_in[3];
    const float* g1o = (const float*)d_in[4];
    float* outp = (float*)d_out;
    dim3 grid(256, Hh / TH);  // 256 planes x 8 row tiles
    dim3 block(256);
    hipLaunchKernelGGL(dtcwt_inv, grid, block, 0, stream,
                       Yl, Yhr, Yhi, g0o, g1o, outp);
}